// Round 2
// baseline (200.930 us; speedup 1.0000x reference)
//
#include <hip/hip_runtime.h>

#define IN   128
#define HID  16
#define OUT  64

// K1: xsxn[i][0..15] = x[i,:] @ W_self1 ; xsxn[i][16..31] = x[i,:] @ W_neigh1
__global__ void k_proj1(const float* __restrict__ x,
                        const float* __restrict__ Ws,
                        const float* __restrict__ Wn,
                        float* __restrict__ xsxn, int n) {
    __shared__ float lw[IN][32];   // 16 KB: combined [W_self1 | W_neigh1]
    __shared__ float lx[8][IN];    // 4 KB: 8 node rows
    int tid = threadIdx.x;  // 256 threads
    for (int i = tid; i < IN * 32; i += 256) {
        int k = i >> 5, j = i & 31;
        lw[k][j] = (j < HID) ? Ws[k * HID + j] : Wn[k * HID + (j - 16)];
    }
    int node0 = blockIdx.x * 8;
    for (int i = tid; i < 8 * IN; i += 256) {
        int r = i >> 7, c = i & 127;
        int node = node0 + r;
        lx[r][c] = (node < n) ? x[(size_t)node * IN + c] : 0.f;
    }
    __syncthreads();
    int r = tid >> 5;     // local node 0..7
    int j = tid & 31;     // output column 0..31
    int node = node0 + r;
    if (node >= n) return;
    float acc = 0.f;
    #pragma unroll
    for (int k = 0; k < IN; ++k) acc += lx[r][k] * lw[k][j];
    xsxn[(size_t)node * 32 + j] = acc;
}

// ---- CSR build: histogram -> exclusive scan -> place ----

__global__ void k_hist(const int* __restrict__ dst, int* __restrict__ hist, int e) {
    int i = blockIdx.x * blockDim.x + threadIdx.x;
    if (i >= e) return;
    atomicAdd(&hist[dst[i]], 1);
}

// per-block exclusive scan of 256 elements; block totals to bsum
__global__ void k_scan_block(const int* __restrict__ hist,
                             int* __restrict__ rowptr,
                             int* __restrict__ bsum, int n) {
    __shared__ int sm[256];
    int tid = threadIdx.x;
    int i = blockIdx.x * 256 + tid;
    int v = (i < n) ? hist[i] : 0;
    sm[tid] = v;
    __syncthreads();
    for (int off = 1; off < 256; off <<= 1) {
        int t = (tid >= off) ? sm[tid - off] : 0;
        __syncthreads();
        sm[tid] += t;
        __syncthreads();
    }
    if (i < n) rowptr[i] = sm[tid] - v;   // exclusive partial
    if (tid == 255) bsum[blockIdx.x] = sm[255];
}

// exclusive scan of block sums (nb <= 256), single block
__global__ void k_scan_bsum(int* __restrict__ bsum, int nb) {
    __shared__ int sm[256];
    int tid = threadIdx.x;
    int v = (tid < nb) ? bsum[tid] : 0;
    sm[tid] = v;
    __syncthreads();
    for (int off = 1; off < 256; off <<= 1) {
        int t = (tid >= off) ? sm[tid - off] : 0;
        __syncthreads();
        sm[tid] += t;
        __syncthreads();
    }
    if (tid < nb) bsum[tid] = sm[tid] - v;
}

// add scanned block offsets; also init cursor copy; set rowptr[n]=e
__global__ void k_scan_add(int* __restrict__ rowptr, const int* __restrict__ bsum,
                           int* __restrict__ cursor, int n, int e) {
    int i = blockIdx.x * 256 + threadIdx.x;
    if (i < n) {
        int r = rowptr[i] + bsum[blockIdx.x];
        rowptr[i] = r;
        cursor[i] = r;
    }
    if (i == 0) rowptr[n] = e;
}

__global__ void k_place(const int* __restrict__ src, const int* __restrict__ dst,
                        int* __restrict__ cursor, int* __restrict__ sorted_src, int e) {
    int i = blockIdx.x * blockDim.x + threadIdx.x;
    if (i >= e) return;
    int pos = atomicAdd(&cursor[dst[i]], 1);
    sorted_src[pos] = src[i];
}

// ---- Layer 1 aggregate (pull, no atomics) fused with finish:
//      h = relu(xs + (sum_nb xn)/deg + b1)
__global__ void k_agg1(const int* __restrict__ rowptr, const int* __restrict__ ssrc,
                       const float* __restrict__ xsxn, const float* __restrict__ b1,
                       float* __restrict__ h, int n) {
    int gid = blockIdx.x * blockDim.x + threadIdx.x;
    int node = gid >> 4, d = gid & 15;
    if (node >= n) return;
    int s0 = rowptr[node], s1 = rowptr[node + 1];
    float acc = 0.f;
    for (int k = s0; k < s1; ++k) {
        int s = ssrc[k];
        acc += xsxn[(size_t)s * 32 + 16 + d];
    }
    float dg = fmaxf((float)(s1 - s0), 1.0f);
    float v = xsxn[(size_t)node * 32 + d] + acc / dg + b1[d];
    h[(size_t)node * HID + d] = fmaxf(v, 0.f);
}

// ---- Layer 2 aggregate (pull): agg2 = sum of neighbor h (raw sum)
__global__ void k_agg2(const int* __restrict__ rowptr, const int* __restrict__ ssrc,
                       const float* __restrict__ h, float* __restrict__ agg2, int n) {
    int gid = blockIdx.x * blockDim.x + threadIdx.x;
    int node = gid >> 4, d = gid & 15;
    if (node >= n) return;
    int s0 = rowptr[node], s1 = rowptr[node + 1];
    float acc = 0.f;
    for (int k = s0; k < s1; ++k) {
        int s = ssrc[k];
        acc += h[(size_t)s * HID + d];
    }
    agg2[(size_t)node * HID + d] = acc;
}

// K5: out = h @ W_self2 + (agg2/deg) @ W_neigh2 + b2
__global__ void k_out(const float* __restrict__ h,
                      const float* __restrict__ agg2,
                      const int* __restrict__ rowptr,
                      const float* __restrict__ Ws2,   // [16,64]
                      const float* __restrict__ Wn2,   // [16,64]
                      const float* __restrict__ b2,
                      float* __restrict__ out, int n) {
    __shared__ float lws[HID][OUT];  // 4 KB
    __shared__ float lwn[HID][OUT];  // 4 KB
    int tid = threadIdx.x;  // 256
    for (int i = tid; i < HID * OUT; i += 256) {
        lws[i >> 6][i & 63] = Ws2[i];
        lwn[i >> 6][i & 63] = Wn2[i];
    }
    __syncthreads();
    int r = tid >> 6;     // local node 0..3 (one wave per node)
    int o = tid & 63;     // output column
    int node = blockIdx.x * 4 + r;
    if (node >= n) return;
    int cnt = rowptr[node + 1] - rowptr[node];
    float inv = 1.0f / fmaxf((float)cnt, 1.0f);
    float acc = b2[o];
    #pragma unroll
    for (int j = 0; j < HID; ++j) {
        float hv = h[(size_t)node * HID + j];
        float av = agg2[(size_t)node * HID + j] * inv;
        acc += hv * lws[j][o] + av * lwn[j][o];
    }
    out[(size_t)node * OUT + o] = acc;
}

extern "C" void kernel_launch(void* const* d_in, const int* in_sizes, int n_in,
                              void* d_out, int out_size, void* d_ws, size_t ws_size,
                              hipStream_t stream) {
    const float* x   = (const float*)d_in[0];
    const int*   src = (const int*)d_in[1];
    const int*   dst = (const int*)d_in[2];
    const float* Ws1 = (const float*)d_in[3];
    const float* Wn1 = (const float*)d_in[4];
    const float* b1  = (const float*)d_in[5];
    const float* Ws2 = (const float*)d_in[6];
    const float* Wn2 = (const float*)d_in[7];
    const float* b2  = (const float*)d_in[8];
    float* out = (float*)d_out;

    int n = in_sizes[0] / IN;   // 50000
    int e = in_sizes[1];        // 800000
    int nblk256 = (n + 255) / 256;   // 196 scan blocks

    // Workspace layout:
    // hist/cursor[n] | bsum[256] | rowptr[n+1] | sorted_src[e] | xsxn[n*32] | h[n*16] | agg2[n*16]
    int* hist_cur   = (int*)d_ws;                 // reused: hist, then cursor
    int* bsum       = hist_cur + n;
    int* rowptr     = bsum + 256;
    int* sorted_src = rowptr + (n + 1);
    float* xsxn = (float*)(sorted_src + e);
    float* h    = xsxn + (size_t)n * 32;
    float* agg2 = h + (size_t)n * HID;

    // Zero histogram every call (harness does not re-poison ws).
    hipMemsetAsync(hist_cur, 0, (size_t)n * sizeof(int), stream);

    k_proj1<<<(n + 7) / 8, 256, 0, stream>>>(x, Ws1, Wn1, xsxn, n);

    int eblk = (e + 255) / 256;
    k_hist<<<eblk, 256, 0, stream>>>(dst, hist_cur, e);
    k_scan_block<<<nblk256, 256, 0, stream>>>(hist_cur, rowptr, bsum, n);
    k_scan_bsum<<<1, 256, 0, stream>>>(bsum, nblk256);
    k_scan_add<<<nblk256, 256, 0, stream>>>(rowptr, bsum, hist_cur, n, e);
    k_place<<<eblk, 256, 0, stream>>>(src, dst, hist_cur, sorted_src, e);

    int aggblk = (n * HID + 255) / 256;
    k_agg1<<<aggblk, 256, 0, stream>>>(rowptr, sorted_src, xsxn, b1, h, n);
    k_agg2<<<aggblk, 256, 0, stream>>>(rowptr, sorted_src, h, agg2, n);

    k_out<<<(n + 3) / 4, 256, 0, stream>>>(h, agg2, rowptr, Ws2, Wn2, b2, out, n);
}